// Round 1
// baseline (437.488 us; speedup 1.0000x reference)
//
#include <hip/hip_runtime.h>

typedef unsigned short u16;
typedef short bf16x8 __attribute__((ext_vector_type(8)));
typedef float f32x4 __attribute__((ext_vector_type(4)));
typedef unsigned short u16x8 __attribute__((ext_vector_type(8)));

#define B_DIM 64
#define C_DIM 2048
#define P_DIM 196
#define K_DIM 512
#define HS_DIM 1024

static __device__ __forceinline__ u16 f2bf(float f) {
    union { float f; unsigned u; } v; v.f = f;
    unsigned r = v.u + 0x7FFF + ((v.u >> 16) & 1);
    return (u16)(r >> 16);
}

static __device__ __forceinline__ float fast_tanh(float a) {
    // tanh(a) = 1 - 2/(exp(2a)+1); handles large |a| gracefully
    float e = __expf(2.f * a);
    return 1.f - 2.f / (e + 1.f);
}

// ---------------- K1: per-(b,c) row stats -> ic = mean(x / max(||x||,eps)) ----
__global__ void k1_rowstats(const float* __restrict__ x, float* __restrict__ ic) {
    int row = blockIdx.x * 4 + (threadIdx.x >> 6);  // [0, B*C)
    int l = threadIdx.x & 63;
    const float* r = x + (size_t)row * P_DIM;
    float a0 = r[l], a1 = r[64 + l], a2 = r[128 + l];
    float a3 = (l < 4) ? r[192 + l] : 0.f;
    float s = a0 + a1 + a2 + a3;
    float q = a0 * a0 + a1 * a1 + a2 * a2 + a3 * a3;
    for (int off = 32; off; off >>= 1) { s += __shfl_down(s, off); q += __shfl_down(q, off); }
    if (l == 0) {
        float n = fmaxf(sqrtf(q), 1e-12f);
        ic[row] = s / ((float)P_DIM * n);
    }
}

// ---------------- K2: u[b,k] = bc[k]+whc[k,:]@h[b,:],  v[b,k] = bs[k]+whs[k,:]@h[b,:]
__global__ void k2_hproj(const float* __restrict__ h, const float* __restrict__ whc,
                         const float* __restrict__ bc, const float* __restrict__ whs,
                         const float* __restrict__ bs, float* __restrict__ u,
                         float* __restrict__ v) {
    int w = blockIdx.x * 4 + (threadIdx.x >> 6);  // [0, B*K)
    int b = w >> 9, k = w & 511;
    int l = threadIdx.x & 63;
    const float* hr = h + (size_t)b * HS_DIM;
    const float* wcr = whc + (size_t)k * HS_DIM;
    const float* wsr = whs + (size_t)k * HS_DIM;
    float su = 0.f, sv = 0.f;
    for (int i = l; i < HS_DIM; i += 64) {
        float hv = hr[i];
        su = fmaf(wcr[i], hv, su);
        sv = fmaf(wsr[i], hv, sv);
    }
    for (int off = 32; off; off >>= 1) { su += __shfl_down(su, off); sv += __shfl_down(sv, off); }
    if (l == 0) { u[w] = su + bc[k]; v[w] = sv + bs[k]; }
}

// ---------------- K2b: ws (f32) -> bf16 ----------------
__global__ void k2b_conv(const float* __restrict__ ws, u16* __restrict__ wsb) {
    int i = blockIdx.x * 256 + threadIdx.x;  // float4 index, total K*C/4
    float4 f = ((const float4*)ws)[i];
    u16 o0 = f2bf(f.x), o1 = f2bf(f.y), o2 = f2bf(f.z), o3 = f2bf(f.w);
    ushort4 o; o.x = o0; o.y = o1; o.z = o2; o.w = o3;
    ((ushort4*)wsb)[i] = o;
}

// ---------------- K3: sc[b,c] = sum_k wci[k]*tanh(wc[k]*ic[b,c]+u[b,k]) + bci --
__global__ void k3_sc(const float* __restrict__ ic, const float* __restrict__ u,
                      const float* __restrict__ wc, const float* __restrict__ wci,
                      const float* __restrict__ bci, float* __restrict__ sc) {
    __shared__ float swc[512], swci[512], su[512];
    int b = blockIdx.y;
    int c = blockIdx.x * 256 + threadIdx.x;
    for (int i = threadIdx.x; i < 512; i += 256) {
        swc[i] = wc[i]; swci[i] = wci[i]; su[i] = u[b * 512 + i];
    }
    __syncthreads();
    float icv = ic[(size_t)b * C_DIM + c];
    float s = 0.f;
    #pragma unroll 8
    for (int k = 0; k < 512; k++) {
        float a = fmaf(swc[k], icv, su[k]);
        s = fmaf(swci[k], fast_tanh(a), s);
    }
    sc[(size_t)b * C_DIM + c] = s + bci[0];
}

// ---------------- K4: softmax over C -> ac ----------------
__global__ void k4_softmax_c(const float* __restrict__ sc, float* __restrict__ ac) {
    int b = blockIdx.x, t = threadIdx.x;
    __shared__ float red[4], red2[4];
    const float* s = sc + (size_t)b * C_DIM;
    float vals[8]; float m = -1e30f;
    #pragma unroll
    for (int i = 0; i < 8; i++) { vals[i] = s[t + i * 256]; m = fmaxf(m, vals[i]); }
    for (int off = 32; off; off >>= 1) m = fmaxf(m, __shfl_xor(m, off));
    if ((t & 63) == 0) red[t >> 6] = m;
    __syncthreads();
    m = fmaxf(fmaxf(red[0], red[1]), fmaxf(red[2], red[3]));
    float sum = 0.f;
    #pragma unroll
    for (int i = 0; i < 8; i++) { vals[i] = __expf(vals[i] - m); sum += vals[i]; }
    for (int off = 32; off; off >>= 1) sum += __shfl_xor(sum, off);
    if ((t & 63) == 0) red2[t >> 6] = sum;
    __syncthreads();
    sum = red2[0] + red2[1] + red2[2] + red2[3];
    float inv = 1.f / sum;
    float* a = ac + (size_t)b * C_DIM;
    #pragma unroll
    for (int i = 0; i < 8; i++) a[t + i * 256] = vals[i] * inv;
}

// ---------------- K5: fused GEMM (ws@xw) + colnorm + tanh + k-reduce -> ss ----
// grid (4 p-tiles, 64 b), 512 threads (8 waves). Per block: M=512 (all k), N=64 p,
// K-loop over C in chunks of 32. mfma_f32_16x16x32_bf16.
__global__ __launch_bounds__(512) void k5_gemm(
    const float* __restrict__ x, const u16* __restrict__ wsb,
    const float* __restrict__ ac, const float* __restrict__ vv,
    const float* __restrict__ wsi, const float* __restrict__ bsi,
    float* __restrict__ ss) {
    __shared__ u16 lds_a[512][40];   // [k-row][c-chunk 32 + pad 8]
    __shared__ u16 lds_b[64][40];    // [p][c-chunk 32 + pad 8]
    __shared__ float lds_red[512];
    __shared__ float lds_cn[64];
    __shared__ float lds_ss[8][64];

    int b = blockIdx.y;
    int p0 = blockIdx.x * 64;
    int t = threadIdx.x;
    int w = t >> 6, l = t & 63;

    f32x4 acc[4][4];
    #pragma unroll
    for (int i = 0; i < 4; i++)
        #pragma unroll
        for (int j = 0; j < 4; j++)
            acc[i][j] = (f32x4){0.f, 0.f, 0.f, 0.f};

    float psum = 0.f;  // column sum-of-squares partial, column pj = t&63

    const int arow = t >> 2;          // A staging: base row
    const int acoff = (t & 3) * 8;    // A staging: ushort offset within 32-c chunk
    const int pj = t & 63;            // B staging column (fixed per thread)

    for (int cc = 0; cc < C_DIM; cc += 32) {
        __syncthreads();
        // ---- stage A: wsb[0..511][cc..cc+32) -> lds_a ----
        {
            const u16* src = wsb + (size_t)arow * C_DIM + cc + acoff;
            #pragma unroll
            for (int rep = 0; rep < 4; rep++) {
                u16x8 val = *(const u16x8*)(src + (size_t)rep * 128 * C_DIM);
                *(u16x8*)(&lds_a[arow + rep * 128][acoff]) = val;
            }
        }
        // ---- stage B: xw[c][p] = x[b][cc+ci][p0+pj]*ac[b][cc+ci] -> lds_b[p][c]
        {
            #pragma unroll
            for (int rep = 0; rep < 4; rep++) {
                int ci = (t >> 6) + rep * 8;
                int p = p0 + pj;
                float xv = (p < P_DIM) ? x[((size_t)b * C_DIM + cc + ci) * P_DIM + p] : 0.f;
                float xw = xv * ac[(size_t)b * C_DIM + cc + ci];
                psum = fmaf(xw, xw, psum);
                lds_b[pj][ci] = f2bf(xw);
            }
        }
        __syncthreads();
        // ---- mfma ----
        bf16x8 af[4], bf[4];
        #pragma unroll
        for (int mt = 0; mt < 4; mt++)
            af[mt] = *(bf16x8*)(&lds_a[w * 64 + mt * 16 + (l & 15)][(l >> 4) * 8]);
        #pragma unroll
        for (int nt = 0; nt < 4; nt++)
            bf[nt] = *(bf16x8*)(&lds_b[nt * 16 + (l & 15)][(l >> 4) * 8]);
        #pragma unroll
        for (int mt = 0; mt < 4; mt++)
            #pragma unroll
            for (int nt = 0; nt < 4; nt++)
                acc[mt][nt] = __builtin_amdgcn_mfma_f32_16x16x32_bf16(
                    af[mt], bf[nt], acc[mt][nt], 0, 0, 0);
    }

    // ---- column norms ----
    __syncthreads();
    lds_red[t] = psum;
    __syncthreads();
    if (t < 64) {
        float cs = 0.f;
        #pragma unroll
        for (int i = 0; i < 8; i++) cs += lds_red[t + i * 64];
        lds_cn[t] = fmaxf(sqrtf(cs), 1e-12f);
    }
    __syncthreads();

    // ---- epilogue: tanh + k-reduction with wsi ----
    float ssv[4] = {0.f, 0.f, 0.f, 0.f};
    int rg = l >> 4;
    #pragma unroll
    for (int mt = 0; mt < 4; mt++) {
        int rbase = w * 64 + mt * 16 + rg * 4;
        #pragma unroll
        for (int j = 0; j < 4; j++) {
            int r = rbase + j;
            float wsiv = wsi[r];
            float vb = vv[b * K_DIM + r];
            #pragma unroll
            for (int nt = 0; nt < 4; nt++) {
                float cn = lds_cn[nt * 16 + (l & 15)];
                float a = acc[mt][nt][j] / cn + vb;
                ssv[nt] = fmaf(wsiv, fast_tanh(a), ssv[nt]);
            }
        }
    }
    #pragma unroll
    for (int nt = 0; nt < 4; nt++) {
        ssv[nt] += __shfl_xor(ssv[nt], 16);
        ssv[nt] += __shfl_xor(ssv[nt], 32);
    }
    if (rg == 0) {
        #pragma unroll
        for (int nt = 0; nt < 4; nt++) lds_ss[w][nt * 16 + l] = ssv[nt];
    }
    __syncthreads();
    if (t < 64) {
        float s = 0.f;
        #pragma unroll
        for (int ww = 0; ww < 8; ww++) s += lds_ss[ww][t];
        int p = p0 + t;
        if (p < P_DIM) ss[b * P_DIM + p] = s + bsi[0];
    }
}

// ---------------- K6: softmax over P -> asp ----------------
__global__ void k6_softmax_p(const float* __restrict__ ss, float* __restrict__ asp) {
    int b = blockIdx.x, t = threadIdx.x;
    __shared__ float red[4], red2[4];
    float val = (t < P_DIM) ? ss[b * P_DIM + t] : -1e30f;
    float m = val;
    for (int off = 32; off; off >>= 1) m = fmaxf(m, __shfl_xor(m, off));
    if ((t & 63) == 0) red[t >> 6] = m;
    __syncthreads();
    m = fmaxf(fmaxf(red[0], red[1]), fmaxf(red[2], red[3]));
    float e = (t < P_DIM) ? __expf(val - m) : 0.f;
    float sum = e;
    for (int off = 32; off; off >>= 1) sum += __shfl_xor(sum, off);
    if ((t & 63) == 0) red2[t >> 6] = sum;
    __syncthreads();
    sum = red2[0] + red2[1] + red2[2] + red2[3];
    if (t < P_DIM) asp[b * P_DIM + t] = e / sum;
}

// ---------------- K7: out = x * ac[b,c] * asp[b,p] ----------------
__global__ void k7_out(const float* __restrict__ x, const float* __restrict__ ac,
                       const float* __restrict__ asp, float* __restrict__ out) {
    int idx = blockIdx.x * 256 + threadIdx.x;  // float4 index; 196 = 49*4
    int row = idx / 49;                        // b*C + c
    int pq = idx - row * 49;
    int b = row >> 11;
    float a = ac[row];
    float4 xv = ((const float4*)x)[idx];
    float4 pv = *(const float4*)&asp[b * P_DIM + pq * 4];
    float4 o;
    o.x = xv.x * a * pv.x;
    o.y = xv.y * a * pv.y;
    o.z = xv.z * a * pv.z;
    o.w = xv.w * a * pv.w;
    ((float4*)out)[idx] = o;
}

extern "C" void kernel_launch(void* const* d_in, const int* in_sizes, int n_in,
                              void* d_out, int out_size, void* d_ws, size_t ws_size,
                              hipStream_t stream) {
    const float* img = (const float*)d_in[0];
    const float* h   = (const float*)d_in[1];
    const float* wc  = (const float*)d_in[2];
    const float* bc  = (const float*)d_in[3];
    const float* whc = (const float*)d_in[4];
    const float* wci = (const float*)d_in[5];
    const float* bci = (const float*)d_in[6];
    const float* ws  = (const float*)d_in[7];
    const float* bs  = (const float*)d_in[8];
    const float* whs = (const float*)d_in[9];
    const float* wsi = (const float*)d_in[10];
    const float* bsi = (const float*)d_in[11];
    float* out = (float*)d_out;

    char* wsp = (char*)d_ws;
    float* ic  = (float*)(wsp);                         // 131072 f
    float* u   = (float*)(wsp + 524288);                // 32768 f
    float* v   = (float*)(wsp + 655360);                // 32768 f
    float* sc  = (float*)(wsp + 786432);                // 131072 f
    float* ac  = (float*)(wsp + 1310720);               // 131072 f
    float* ssb = (float*)(wsp + 1835008);               // 12544 f
    float* asp = (float*)(wsp + 1888256);               // 12544 f
    u16*   wsb = (u16*)  (wsp + 1941504);               // 1M u16 (2 MB)

    k1_rowstats<<<dim3(32768), dim3(256), 0, stream>>>(img, ic);
    k2_hproj<<<dim3(8192), dim3(256), 0, stream>>>(h, whc, bc, whs, bs, u, v);
    k2b_conv<<<dim3(1024), dim3(256), 0, stream>>>(ws, wsb);
    k3_sc<<<dim3(8, 64), dim3(256), 0, stream>>>(ic, u, wc, wci, bci, sc);
    k4_softmax_c<<<dim3(64), dim3(256), 0, stream>>>(sc, ac);
    k5_gemm<<<dim3(4, 64), dim3(512), 0, stream>>>(img, wsb, ac, v, wsi, bsi, ssb);
    k6_softmax_p<<<dim3(64), dim3(256), 0, stream>>>(ssb, asp);
    k7_out<<<dim3(25088), dim3(256), 0, stream>>>(img, ac, asp, out);
}

// Round 3
// 420.108 us; speedup vs baseline: 1.0414x; 1.0414x over previous
//
#include <hip/hip_runtime.h>

typedef unsigned short u16;
typedef short bf16x8 __attribute__((ext_vector_type(8)));
typedef float f32x4 __attribute__((ext_vector_type(4)));
typedef unsigned short u16x8 __attribute__((ext_vector_type(8)));

typedef __attribute__((address_space(3))) unsigned int lds_u32;
typedef const __attribute__((address_space(1))) unsigned int glb_u32;

#define B_DIM 64
#define C_DIM 2048
#define P_DIM 196
#define K_DIM 512
#define HS_DIM 1024

static __device__ __forceinline__ u16 f2bf(float f) {
    union { float f; unsigned u; } v; v.f = f;
    unsigned r = v.u + 0x7FFF + ((v.u >> 16) & 1);
    return (u16)(r >> 16);
}

static __device__ __forceinline__ float fast_tanh(float a) {
    float e = __expf(2.f * a);
    return 1.f - 2.f / (e + 1.f);
}

static __device__ __forceinline__ void gload_lds16(const void* g, void* l) {
    __builtin_amdgcn_global_load_lds((glb_u32*)g, (lds_u32*)l, 16, 0, 0);
}

// ---------------- K1: per-(b,c) row stats -> ic = mean(x / max(||x||,eps)) ----
__global__ void k1_rowstats(const float* __restrict__ x, float* __restrict__ ic) {
    int row = blockIdx.x * 4 + (threadIdx.x >> 6);  // [0, B*C)
    int l = threadIdx.x & 63;
    const float* r = x + (size_t)row * P_DIM;
    float a0 = r[l], a1 = r[64 + l], a2 = r[128 + l];
    float a3 = (l < 4) ? r[192 + l] : 0.f;
    float s = a0 + a1 + a2 + a3;
    float q = a0 * a0 + a1 * a1 + a2 * a2 + a3 * a3;
    for (int off = 32; off; off >>= 1) { s += __shfl_down(s, off); q += __shfl_down(q, off); }
    if (l == 0) {
        float n = fmaxf(sqrtf(q), 1e-12f);
        ic[row] = s / ((float)P_DIM * n);
    }
}

// ---------------- K2: u[b,k] = bc[k]+whc[k,:]@h[b,:],  v[b,k] = bs[k]+whs[k,:]@h[b,:]
// One block per k; whc/whs rows staged in LDS; loop over b (h stays L2-hot).
__global__ __launch_bounds__(256) void k2_hproj(
    const float* __restrict__ h, const float* __restrict__ whc,
    const float* __restrict__ bc, const float* __restrict__ whs,
    const float* __restrict__ bs, float* __restrict__ u, float* __restrict__ v) {
    __shared__ float rc[1024], rs[1024];
    int k = blockIdx.x;
    int t = threadIdx.x, w = t >> 6, l = t & 63;
    for (int i = t; i < 1024; i += 256) {
        rc[i] = whc[(size_t)k * HS_DIM + i];
        rs[i] = whs[(size_t)k * HS_DIM + i];
    }
    __syncthreads();
    float bcv = bc[k], bsv = bs[k];
    for (int bb = 0; bb < 16; ++bb) {
        int b = (w << 4) + bb;
        const float* hr = h + (size_t)b * HS_DIM;
        float su = 0.f, sv = 0.f;
        #pragma unroll
        for (int j = 0; j < 16; ++j) {
            float hv = hr[l + (j << 6)];
            su = fmaf(rc[l + (j << 6)], hv, su);
            sv = fmaf(rs[l + (j << 6)], hv, sv);
        }
        #pragma unroll
        for (int off = 32; off; off >>= 1) { su += __shfl_down(su, off); sv += __shfl_down(sv, off); }
        if (l == 0) { u[b * K_DIM + k] = su + bcv; v[b * K_DIM + k] = sv + bsv; }
    }
}

// ---------------- K2b: ws (f32) -> bf16 ----------------
__global__ void k2b_conv(const float* __restrict__ ws, u16* __restrict__ wsb) {
    int i = blockIdx.x * 256 + threadIdx.x;  // float4 index, total K*C/4
    float4 f = ((const float4*)ws)[i];
    ushort4 o; o.x = f2bf(f.x); o.y = f2bf(f.y); o.z = f2bf(f.z); o.w = f2bf(f.w);
    ((ushort4*)wsb)[i] = o;
}

// ---------------- K3: sc[b,c] = sum_k wci[k]*tanh(wc[k]*ic[b,c]+u[b,k]) + bci --
__global__ void k3_sc(const float* __restrict__ ic, const float* __restrict__ u,
                      const float* __restrict__ wc, const float* __restrict__ wci,
                      const float* __restrict__ bci, float* __restrict__ sc) {
    __shared__ float swc[512], swci[512], su[512];
    int b = blockIdx.y;
    int c = blockIdx.x * 256 + threadIdx.x;
    for (int i = threadIdx.x; i < 512; i += 256) {
        swc[i] = wc[i]; swci[i] = wci[i]; su[i] = u[b * 512 + i];
    }
    __syncthreads();
    float icv = ic[(size_t)b * C_DIM + c];
    float s = 0.f;
    #pragma unroll 8
    for (int k = 0; k < 512; k++) {
        float a = fmaf(swc[k], icv, su[k]);
        s = fmaf(swci[k], fast_tanh(a), s);
    }
    sc[(size_t)b * C_DIM + c] = s + bci[0];
}

// ---------------- K4: softmax over C -> ac ----------------
__global__ void k4_softmax_c(const float* __restrict__ sc, float* __restrict__ ac) {
    int b = blockIdx.x, t = threadIdx.x;
    __shared__ float red[4], red2[4];
    const float* s = sc + (size_t)b * C_DIM;
    float vals[8]; float m = -1e30f;
    #pragma unroll
    for (int i = 0; i < 8; i++) { vals[i] = s[t + i * 256]; m = fmaxf(m, vals[i]); }
    for (int off = 32; off; off >>= 1) m = fmaxf(m, __shfl_xor(m, off));
    if ((t & 63) == 0) red[t >> 6] = m;
    __syncthreads();
    m = fmaxf(fmaxf(red[0], red[1]), fmaxf(red[2], red[3]));
    float sum = 0.f;
    #pragma unroll
    for (int i = 0; i < 8; i++) { vals[i] = __expf(vals[i] - m); sum += vals[i]; }
    for (int off = 32; off; off >>= 1) sum += __shfl_xor(sum, off);
    if ((t & 63) == 0) red2[t >> 6] = sum;
    __syncthreads();
    sum = red2[0] + red2[1] + red2[2] + red2[3];
    float inv = 1.f / sum;
    float* a = ac + (size_t)b * C_DIM;
    #pragma unroll
    for (int i = 0; i < 8; i++) a[t + i * 256] = vals[i] * inv;
}

// ---------------- K5: fused GEMM (ws@xw) + colnorm + tanh + k-reduce -> ssp ----
// grid (4 ptiles, 2 ksplit, 64 b) = 512 blocks, 256 threads (4 waves).
// Block: rows [ks*256, +256), cols [ptile*64, +64). BK=32, double-buffered,
// one barrier per K-step. A via global_load_lds (source pre-swizzled),
// B reg-staged with swizzled ds_write_b128. Swizzle: 16B-slot ^= (row>>1)&3.
__global__ __launch_bounds__(256, 2) void k5_gemm(
    const float* __restrict__ x, const u16* __restrict__ wsb,
    const float* __restrict__ ac, const float* __restrict__ vv,
    const float* __restrict__ wsi, float* __restrict__ ssp) {
    __shared__ __align__(16) u16 lA[2][256 * 32];
    __shared__ __align__(16) u16 lB[2][64 * 32];
    __shared__ float lred[256];
    __shared__ float lcn[64];
    __shared__ float lss[4][64];

    const int p0 = blockIdx.x * 64;
    const int Rb = blockIdx.y * 256;
    const int b  = blockIdx.z;
    const int t = threadIdx.x;
    const int w = t >> 6, l = t & 63;
    const int lr16 = l & 15, lh = l >> 4;
    const int a_lr = l >> 2, a_lc = l & 3;

    const int pg = t & 63;
    const int co = (t >> 6) << 3;   // this thread's 8-c group for B staging
    const int pp = p0 + pg;
    const bool pv = pp < P_DIM;
    const int sBw = (pg >> 1) & 3;

    f32x4 acc[4][4];
    #pragma unroll
    for (int i = 0; i < 4; i++)
        #pragma unroll
        for (int j = 0; j < 4; j++)
            acc[i][j] = (f32x4){0.f, 0.f, 0.f, 0.f};

    float psum = 0.f;
    const float* xcol = x + (size_t)b * C_DIM * P_DIM + pp;
    const float* acrow = ac + (size_t)b * C_DIM;

    auto STAGE_A = [&](int cc, int bufi) {
        #pragma unroll
        for (int q = 0; q < 4; ++q) {
            int chunk = (w << 2) + q;
            int r = (chunk << 4) + a_lr;
            int s = (r >> 1) & 3;
            const u16* src = wsb + ((size_t)(Rb + r) << 11) + cc + ((a_lc ^ s) << 3);
            gload_lds16(src, &lA[bufi][chunk << 9]);
        }
    };
    auto LOAD_B = [&](int cc, float* xv, float* av) {
        #pragma unroll
        for (int j = 0; j < 8; ++j) {
            xv[j] = pv ? xcol[(size_t)(cc + co + j) * P_DIM] : 0.f;
            av[j] = acrow[cc + co + j];
        }
    };
    auto PROC_B = [&](const float* xv, const float* av, int bufi) {
        u16x8 pk;
        #pragma unroll
        for (int j = 0; j < 8; ++j) {
            float xw = xv[j] * av[j];
            psum = fmaf(xw, xw, psum);
            pk[j] = f2bf(xw);
        }
        *(u16x8*)&lB[bufi][(pg << 5) + (((t >> 6) ^ sBw) << 3)] = pk;
    };

    {
        float xv0[8], av0[8];
        STAGE_A(0, 0);
        LOAD_B(0, xv0, av0);
        PROC_B(xv0, av0, 0);
    }
    __syncthreads();

    int cur = 0;
    for (int it = 0; it < 64; ++it) {
        int cc = it << 5;
        float xv[8], av[8];
        const bool pf = it < 63;
        if (pf) {
            STAGE_A(cc + 32, cur ^ 1);
            LOAD_B(cc + 32, xv, av);
        }
        bf16x8 af[4], bfr[4];
        #pragma unroll
        for (int mt = 0; mt < 4; ++mt) {
            int r = (w << 6) + (mt << 4) + lr16;
            int s = (r >> 1) & 3;
            af[mt] = *(const bf16x8*)&lA[cur][(r << 5) + ((lh ^ s) << 3)];
        }
        #pragma unroll
        for (int nt = 0; nt < 4; ++nt) {
            int r = (nt << 4) + lr16;
            int s = (r >> 1) & 3;
            bfr[nt] = *(const bf16x8*)&lB[cur][(r << 5) + ((lh ^ s) << 3)];
        }
        #pragma unroll
        for (int mt = 0; mt < 4; ++mt)
            #pragma unroll
            for (int nt = 0; nt < 4; ++nt)
                acc[mt][nt] = __builtin_amdgcn_mfma_f32_16x16x32_bf16(
                    af[mt], bfr[nt], acc[mt][nt], 0, 0, 0);
        if (pf) PROC_B(xv, av, cur ^ 1);
        __syncthreads();
        cur ^= 1;
    }

    // ---- column norms (each block redundantly covers full C: self-contained) ----
    lred[t] = psum;
    __syncthreads();
    if (t < 64) {
        float cs = lred[t] + lred[t + 64] + lred[t + 128] + lred[t + 192];
        lcn[t] = fmaxf(sqrtf(cs), 1e-12f);
    }
    __syncthreads();

    // ---- epilogue: tanh + partial k-reduction with wsi ----
    float ssv[4] = {0.f, 0.f, 0.f, 0.f};
    #pragma unroll
    for (int mt = 0; mt < 4; ++mt) {
        int rl = (w << 6) + (mt << 4) + (lh << 2);
        #pragma unroll
        for (int j = 0; j < 4; ++j) {
            int r = Rb + rl + j;
            float wsiv = wsi[r];
            float vb = vv[b * K_DIM + r];
            #pragma unroll
            for (int nt = 0; nt < 4; ++nt) {
                float cn = lcn[(nt << 4) + lr16];
                float a = acc[mt][nt][j] / cn + vb;
                ssv[nt] = fmaf(wsiv, fast_tanh(a), ssv[nt]);
            }
        }
    }
    #pragma unroll
    for (int nt = 0; nt < 4; ++nt) {
        ssv[nt] += __shfl_xor(ssv[nt], 16);
        ssv[nt] += __shfl_xor(ssv[nt], 32);
    }
    if (lh == 0) {
        #pragma unroll
        for (int nt = 0; nt < 4; ++nt) lss[w][(nt << 4) + lr16] = ssv[nt];
    }
    __syncthreads();
    if (t < 64) {
        float s = lss[0][t] + lss[1][t] + lss[2][t] + lss[3][t];
        ssp[((blockIdx.y << 6) + b) * 256 + p0 + t] = s;
    }
}

// ---------------- K6: softmax over P (sums the 2 k-split partials) ----------------
__global__ void k6_softmax_p(const float* __restrict__ ssp, const float* __restrict__ bsi,
                             float* __restrict__ asp) {
    int b = blockIdx.x, t = threadIdx.x;
    __shared__ float red[4], red2[4];
    float val = -1e30f;
    if (t < P_DIM) val = ssp[b * 256 + t] + ssp[(64 + b) * 256 + t] + bsi[0];
    float m = val;
    for (int off = 32; off; off >>= 1) m = fmaxf(m, __shfl_xor(m, off));
    if ((t & 63) == 0) red[t >> 6] = m;
    __syncthreads();
    m = fmaxf(fmaxf(red[0], red[1]), fmaxf(red[2], red[3]));
    float e = (t < P_DIM) ? __expf(val - m) : 0.f;
    float sum = e;
    for (int off = 32; off; off >>= 1) sum += __shfl_xor(sum, off);
    if ((t & 63) == 0) red2[t >> 6] = sum;
    __syncthreads();
    sum = red2[0] + red2[1] + red2[2] + red2[3];
    if (t < P_DIM) asp[b * P_DIM + t] = e / sum;
}

// ---------------- K7: out = x * ac[b,c] * asp[b,p] ----------------
__global__ void k7_out(const float* __restrict__ x, const float* __restrict__ ac,
                       const float* __restrict__ asp, float* __restrict__ out) {
    int idx = blockIdx.x * 256 + threadIdx.x;  // float4 index; 196 = 49*4
    int row = idx / 49;                        // b*C + c
    int pq = idx - row * 49;
    int b = row >> 11;
    float a = ac[row];
    float4 xv = ((const float4*)x)[idx];
    float4 pv = *(const float4*)&asp[b * P_DIM + pq * 4];
    float4 o;
    o.x = xv.x * a * pv.x;
    o.y = xv.y * a * pv.y;
    o.z = xv.z * a * pv.z;
    o.w = xv.w * a * pv.w;
    ((float4*)out)[idx] = o;
}

extern "C" void kernel_launch(void* const* d_in, const int* in_sizes, int n_in,
                              void* d_out, int out_size, void* d_ws, size_t ws_size,
                              hipStream_t stream) {
    const float* img = (const float*)d_in[0];
    const float* h   = (const float*)d_in[1];
    const float* wc  = (const float*)d_in[2];
    const float* bc  = (const float*)d_in[3];
    const float* whc = (const float*)d_in[4];
    const float* wci = (const float*)d_in[5];
    const float* bci = (const float*)d_in[6];
    const float* ws  = (const float*)d_in[7];
    const float* bs  = (const float*)d_in[8];
    const float* whs = (const float*)d_in[9];
    const float* wsi = (const float*)d_in[10];
    const float* bsi = (const float*)d_in[11];
    float* out = (float*)d_out;

    char* wsp = (char*)d_ws;
    float* ic  = (float*)(wsp);                // 512 KB
    float* u   = (float*)(wsp + 524288);       // 128 KB
    float* v   = (float*)(wsp + 655360);       // 128 KB
    float* sc  = (float*)(wsp + 786432);       // 512 KB
    float* ac  = (float*)(wsp + 1310720);      // 512 KB
    float* ssp = (float*)(wsp + 1835008);      // 128 KB [2][64][256]
    float* asp = (float*)(wsp + 1966080);      // 50 KB
    u16*   wsb = (u16*)  (wsp + 2097152);      // 2 MB

    k1_rowstats<<<dim3(32768), dim3(256), 0, stream>>>(img, ic);
    k2_hproj<<<dim3(512), dim3(256), 0, stream>>>(h, whc, bc, whs, bs, u, v);
    k2b_conv<<<dim3(1024), dim3(256), 0, stream>>>(ws, wsb);
    k3_sc<<<dim3(8, 64), dim3(256), 0, stream>>>(ic, u, wc, wci, bci, sc);
    k4_softmax_c<<<dim3(64), dim3(256), 0, stream>>>(sc, ac);
    k5_gemm<<<dim3(4, 2, 64), dim3(256), 0, stream>>>(img, wsb, ac, v, wsi, ssp);
    k6_softmax_p<<<dim3(64), dim3(256), 0, stream>>>(ssp, bsi, asp);
    k7_out<<<dim3(25088), dim3(256), 0, stream>>>(img, ac, asp, out);
}

// Round 4
// 332.130 us; speedup vs baseline: 1.3172x; 1.2649x over previous
//
#include <hip/hip_runtime.h>

typedef unsigned short u16;
typedef short bf16x8 __attribute__((ext_vector_type(8)));
typedef float f32x4 __attribute__((ext_vector_type(4)));
typedef unsigned short u16x8 __attribute__((ext_vector_type(8)));

#define B_DIM 64
#define C_DIM 2048
#define P_DIM 196
#define K_DIM 512
#define HS_DIM 1024

static __device__ __forceinline__ u16 f2bf(float f) {
    union { float f; unsigned u; } v; v.f = f;
    unsigned r = v.u + 0x7FFF + ((v.u >> 16) & 1);
    return (u16)(r >> 16);
}

static __device__ __forceinline__ float fast_tanh(float a) {
    float e = __expf(2.f * a);
    return 1.f - 2.f / (e + 1.f);
}

// ---------------- K1: per-(b,c) row stats -> ic = mean(x / max(||x||,eps)) ----
__global__ void k1_rowstats(const float* __restrict__ x, float* __restrict__ ic) {
    int row = blockIdx.x * 4 + (threadIdx.x >> 6);  // [0, B*C)
    int l = threadIdx.x & 63;
    const float* r = x + (size_t)row * P_DIM;
    float a0 = r[l], a1 = r[64 + l], a2 = r[128 + l];
    float a3 = (l < 4) ? r[192 + l] : 0.f;
    float s = a0 + a1 + a2 + a3;
    float q = a0 * a0 + a1 * a1 + a2 * a2 + a3 * a3;
    for (int off = 32; off; off >>= 1) { s += __shfl_down(s, off); q += __shfl_down(q, off); }
    if (l == 0) {
        float n = fmaxf(sqrtf(q), 1e-12f);
        ic[row] = s / ((float)P_DIM * n);
    }
}

// ---------------- K2: u[b,k] = bc[k]+whc[k,:]@h[b,:],  v[b,k] = bs[k]+whs[k,:]@h[b,:]
__global__ __launch_bounds__(256) void k2_hproj(
    const float* __restrict__ h, const float* __restrict__ whc,
    const float* __restrict__ bc, const float* __restrict__ whs,
    const float* __restrict__ bs, float* __restrict__ u, float* __restrict__ v) {
    __shared__ float rc[1024], rs[1024];
    int k = blockIdx.x;
    int t = threadIdx.x, w = t >> 6, l = t & 63;
    for (int i = t; i < 1024; i += 256) {
        rc[i] = whc[(size_t)k * HS_DIM + i];
        rs[i] = whs[(size_t)k * HS_DIM + i];
    }
    __syncthreads();
    float bcv = bc[k], bsv = bs[k];
    for (int bb = 0; bb < 16; ++bb) {
        int b = (w << 4) + bb;
        const float* hr = h + (size_t)b * HS_DIM;
        float su = 0.f, sv = 0.f;
        #pragma unroll
        for (int j = 0; j < 16; ++j) {
            float hv = hr[l + (j << 6)];
            su = fmaf(rc[l + (j << 6)], hv, su);
            sv = fmaf(rs[l + (j << 6)], hv, sv);
        }
        #pragma unroll
        for (int off = 32; off; off >>= 1) { su += __shfl_down(su, off); sv += __shfl_down(sv, off); }
        if (l == 0) { u[b * K_DIM + k] = su + bcv; v[b * K_DIM + k] = sv + bsv; }
    }
}

// ---------------- K2b: repack ws f32[512][2048] -> fragment-native bf16 ----
// chunk i (16B): lane=i&63, kb=(i>>6)&31, cstep=i>>11
// holds rows r=kb*16+(lane&15), c = cstep*32 + (lane>>4)*8 .. +8
__global__ void k2b_conv(const float* __restrict__ ws, u16* __restrict__ wsb2) {
    int i = blockIdx.x * 256 + threadIdx.x;   // 131072 chunks
    int lane = i & 63;
    int kb = (i >> 6) & 31;
    int cstep = i >> 11;
    int r = kb * 16 + (lane & 15);
    int c0 = (cstep << 5) + ((lane >> 4) << 3);
    const float* src = ws + (size_t)r * C_DIM + c0;
    float4 f0 = *(const float4*)(src);
    float4 f1 = *(const float4*)(src + 4);
    u16x8 o;
    o[0] = f2bf(f0.x); o[1] = f2bf(f0.y); o[2] = f2bf(f0.z); o[3] = f2bf(f0.w);
    o[4] = f2bf(f1.x); o[5] = f2bf(f1.y); o[6] = f2bf(f1.z); o[7] = f2bf(f1.w);
    *(u16x8*)(wsb2 + (size_t)i * 8) = o;
}

// ---------------- K3: sc[b,c] = sum_k wci[k]*tanh(wc[k]*ic[b,c]+u[b,k]) + bci --
__global__ void k3_sc(const float* __restrict__ ic, const float* __restrict__ u,
                      const float* __restrict__ wc, const float* __restrict__ wci,
                      const float* __restrict__ bci, float* __restrict__ sc) {
    __shared__ float swc[512], swci[512], su[512];
    int b = blockIdx.y;
    int c = blockIdx.x * 256 + threadIdx.x;
    for (int i = threadIdx.x; i < 512; i += 256) {
        swc[i] = wc[i]; swci[i] = wci[i]; su[i] = u[b * 512 + i];
    }
    __syncthreads();
    float icv = ic[(size_t)b * C_DIM + c];
    float s = 0.f;
    #pragma unroll 8
    for (int k = 0; k < 512; k++) {
        float a = fmaf(swc[k], icv, su[k]);
        s = fmaf(swci[k], fast_tanh(a), s);
    }
    sc[(size_t)b * C_DIM + c] = s + bci[0];
}

// ---------------- K4: softmax over C -> ac ----------------
__global__ void k4_softmax_c(const float* __restrict__ sc, float* __restrict__ ac) {
    int b = blockIdx.x, t = threadIdx.x;
    __shared__ float red[4], red2[4];
    const float* s = sc + (size_t)b * C_DIM;
    float vals[8]; float m = -1e30f;
    #pragma unroll
    for (int i = 0; i < 8; i++) { vals[i] = s[t + i * 256]; m = fmaxf(m, vals[i]); }
    for (int off = 32; off; off >>= 1) m = fmaxf(m, __shfl_xor(m, off));
    if ((t & 63) == 0) red[t >> 6] = m;
    __syncthreads();
    m = fmaxf(fmaxf(red[0], red[1]), fmaxf(red[2], red[3]));
    float sum = 0.f;
    #pragma unroll
    for (int i = 0; i < 8; i++) { vals[i] = __expf(vals[i] - m); sum += vals[i]; }
    for (int off = 32; off; off >>= 1) sum += __shfl_xor(sum, off);
    if ((t & 63) == 0) red2[t >> 6] = sum;
    __syncthreads();
    sum = red2[0] + red2[1] + red2[2] + red2[3];
    float inv = 1.f / sum;
    float* a = ac + (size_t)b * C_DIM;
    #pragma unroll
    for (int i = 0; i < 8; i++) a[t + i * 256] = vals[i] * inv;
}

// ---------------- K5: fused GEMM (ws@xw) + colnorm + tanh + k-reduce -> ssp ----
// grid (4 ptiles, 2 ksplit, 64 b), 256 thr (4 waves).
// A: fragment-native repacked global -> regs, 2-step prefetch, 4 rotating sets.
// B: x*ac -> f2bf -> swizzled LDS transpose, double-buffered, x-regs 2-step ahead.
// Sync: raw s_barrier + manual lgkmcnt(0) only (no vmcnt drain at barriers).
__global__ __launch_bounds__(256, 2) void k5_gemm(
    const float* __restrict__ x, const u16* __restrict__ wsb2,
    const float* __restrict__ ac, const float* __restrict__ vv,
    const float* __restrict__ wsi, float* __restrict__ ssp) {
    __shared__ __align__(16) u16 lB[2][64 * 32];
    __shared__ float lred[256];
    __shared__ float lcn[64];
    __shared__ float lss[4][64];

    const int p0 = blockIdx.x * 64;
    const int Rb = blockIdx.y * 256;
    const int b  = blockIdx.z;
    const int t = threadIdx.x;
    const int w = t >> 6, l = t & 63;
    const int lr16 = l & 15, lh = l >> 4;
    const int pg = l;
    const int co = w << 3;
    const int pp = p0 + pg;
    const bool pvld = pp < P_DIM;
    const int sBw = (pg >> 1) & 3;

    f32x4 acc[4][4];
    #pragma unroll
    for (int i = 0; i < 4; i++)
        #pragma unroll
        for (int j = 0; j < 4; j++)
            acc[i][j] = (f32x4){0.f, 0.f, 0.f, 0.f};

    float psum = 0.f;
    const float* xcol = x + (size_t)b * (C_DIM * P_DIM) + pp;
    const float* acrow = ac + (size_t)b * C_DIM;
    const bf16x8* abase = (const bf16x8*)wsb2 + ((Rb >> 4) + (w << 2)) * 64 + l;

    float xv[2][8], av[2][8];
    bf16x8 af[4][4];

    auto LOADX = [&](int step, int xs) {
        const int cc = (step << 5) + co;
        #pragma unroll
        for (int j = 0; j < 8; ++j)
            xv[xs][j] = pvld ? xcol[(size_t)(cc + j) * P_DIM] : 0.f;
        float4 a0 = *(const float4*)(acrow + cc);
        float4 a1 = *(const float4*)(acrow + cc + 4);
        av[xs][0] = a0.x; av[xs][1] = a0.y; av[xs][2] = a0.z; av[xs][3] = a0.w;
        av[xs][4] = a1.x; av[xs][5] = a1.y; av[xs][6] = a1.z; av[xs][7] = a1.w;
    };
    auto LOADA = [&](int step, int as_) {
        const bf16x8* p = abase + (size_t)step * 2048;
        #pragma unroll
        for (int mt = 0; mt < 4; ++mt) af[as_][mt] = p[mt * 64];
    };
    auto PROCB = [&](int xs, int bufi) {
        u16x8 pk;
        #pragma unroll
        for (int j = 0; j < 8; ++j) {
            float xw = xv[xs][j] * av[xs][j];
            psum = fmaf(xw, xw, psum);
            pk[j] = f2bf(xw);
        }
        *(u16x8*)&lB[bufi][(pg << 5) + ((w ^ sBw) << 3)] = pk;
    };
    auto RD_B = [&](int bufi, bf16x8* bfr) {
        #pragma unroll
        for (int nt = 0; nt < 4; ++nt) {
            int r = (nt << 4) + lr16;
            int s = (r >> 1) & 3;
            bfr[nt] = *(const bf16x8*)&lB[bufi][(r << 5) + ((lh ^ s) << 3)];
        }
    };
    auto MFMA16 = [&](int as_, const bf16x8* bfr) {
        __builtin_amdgcn_s_setprio(1);
        #pragma unroll
        for (int mt = 0; mt < 4; ++mt)
            #pragma unroll
            for (int nt = 0; nt < 4; ++nt)
                acc[mt][nt] = __builtin_amdgcn_mfma_f32_16x16x32_bf16(
                    af[as_][mt], bfr[nt], acc[mt][nt], 0, 0, 0);
        __builtin_amdgcn_s_setprio(0);
    };

    // prologue: X0,A0,X1,A1 in flight; B(step0) staged
    LOADX(0, 0); LOADA(0, 0);
    LOADX(1, 1); LOADA(1, 1);
    PROCB(0, 0);
    asm volatile("s_waitcnt lgkmcnt(0)" ::: "memory");
    __builtin_amdgcn_s_barrier();

    for (int ii = 0; ii < 15; ++ii) {
        const int base = ii << 2;
        #pragma unroll
        for (int S = 0; S < 4; ++S) {
            bf16x8 bfr[4];
            RD_B(S & 1, bfr);
            LOADX(base + S + 2, S & 1);
            LOADA(base + S + 2, (S + 2) & 3);
            MFMA16(S & 3, bfr);
            PROCB((S + 1) & 1, (S + 1) & 1);
            asm volatile("s_waitcnt lgkmcnt(0)" ::: "memory");
            __builtin_amdgcn_s_barrier();
        }
    }
    // tail: steps 60..63
    #pragma unroll
    for (int S = 0; S < 4; ++S) {
        bf16x8 bfr[4];
        RD_B(S & 1, bfr);
        if (S < 2) { LOADX(62 + S, S & 1); LOADA(62 + S, (S + 2) & 3); }
        MFMA16(S & 3, bfr);
        if (S < 3) PROCB((S + 1) & 1, (S + 1) & 1);
        asm volatile("s_waitcnt lgkmcnt(0)" ::: "memory");
        __builtin_amdgcn_s_barrier();
    }

    // ---- column norms (block covers full C: self-contained) ----
    lred[t] = psum;
    __syncthreads();
    if (t < 64) {
        float cs = lred[t] + lred[t + 64] + lred[t + 128] + lred[t + 192];
        lcn[t] = fmaxf(sqrtf(cs), 1e-12f);
    }
    __syncthreads();

    // ---- epilogue: tanh + partial k-reduction with wsi ----
    float ssv[4] = {0.f, 0.f, 0.f, 0.f};
    #pragma unroll
    for (int mt = 0; mt < 4; ++mt) {
        int rl = (w << 6) + (mt << 4) + (lh << 2);
        #pragma unroll
        for (int j = 0; j < 4; ++j) {
            int r = Rb + rl + j;
            float wsiv = wsi[r];
            float vb = vv[b * K_DIM + r];
            #pragma unroll
            for (int nt = 0; nt < 4; ++nt) {
                float cn = lcn[(nt << 4) + lr16];
                float a = acc[mt][nt][j] / cn + vb;
                ssv[nt] = fmaf(wsiv, fast_tanh(a), ssv[nt]);
            }
        }
    }
    #pragma unroll
    for (int nt = 0; nt < 4; ++nt) {
        ssv[nt] += __shfl_xor(ssv[nt], 16);
        ssv[nt] += __shfl_xor(ssv[nt], 32);
    }
    if (lh == 0) {
        #pragma unroll
        for (int nt = 0; nt < 4; ++nt) lss[w][(nt << 4) + lr16] = ssv[nt];
    }
    __syncthreads();
    if (t < 64) {
        float s = lss[0][t] + lss[1][t] + lss[2][t] + lss[3][t];
        ssp[((blockIdx.y << 6) + b) * 256 + p0 + t] = s;
    }
}

// ---------------- K6: softmax over P (sums the 2 k-split partials) ----------------
__global__ void k6_softmax_p(const float* __restrict__ ssp, const float* __restrict__ bsi,
                             float* __restrict__ asp) {
    int b = blockIdx.x, t = threadIdx.x;
    __shared__ float red[4], red2[4];
    float val = -1e30f;
    if (t < P_DIM) val = ssp[b * 256 + t] + ssp[(64 + b) * 256 + t] + bsi[0];
    float m = val;
    for (int off = 32; off; off >>= 1) m = fmaxf(m, __shfl_xor(m, off));
    if ((t & 63) == 0) red[t >> 6] = m;
    __syncthreads();
    m = fmaxf(fmaxf(red[0], red[1]), fmaxf(red[2], red[3]));
    float e = (t < P_DIM) ? __expf(val - m) : 0.f;
    float sum = e;
    for (int off = 32; off; off >>= 1) sum += __shfl_xor(sum, off);
    if ((t & 63) == 0) red2[t >> 6] = sum;
    __syncthreads();
    sum = red2[0] + red2[1] + red2[2] + red2[3];
    if (t < P_DIM) asp[b * P_DIM + t] = e / sum;
}

// ---------------- K7: out = x * ac[b,c] * asp[b,p] ----------------
__global__ void k7_out(const float* __restrict__ x, const float* __restrict__ ac,
                       const float* __restrict__ asp, float* __restrict__ out) {
    int idx = blockIdx.x * 256 + threadIdx.x;  // float4 index; 196 = 49*4
    int row = idx / 49;                        // b*C + c
    int pq = idx - row * 49;
    int b = row >> 11;
    float a = ac[row];
    float4 xv = ((const float4*)x)[idx];
    float4 pv = *(const float4*)&asp[b * P_DIM + pq * 4];
    float4 o;
    o.x = xv.x * a * pv.x;
    o.y = xv.y * a * pv.y;
    o.z = xv.z * a * pv.z;
    o.w = xv.w * a * pv.w;
    ((float4*)out)[idx] = o;
}

extern "C" void kernel_launch(void* const* d_in, const int* in_sizes, int n_in,
                              void* d_out, int out_size, void* d_ws, size_t ws_size,
                              hipStream_t stream) {
    const float* img = (const float*)d_in[0];
    const float* h   = (const float*)d_in[1];
    const float* wc  = (const float*)d_in[2];
    const float* bc  = (const float*)d_in[3];
    const float* whc = (const float*)d_in[4];
    const float* wci = (const float*)d_in[5];
    const float* bci = (const float*)d_in[6];
    const float* ws  = (const float*)d_in[7];
    const float* bs  = (const float*)d_in[8];
    const float* whs = (const float*)d_in[9];
    const float* wsi = (const float*)d_in[10];
    const float* bsi = (const float*)d_in[11];
    float* out = (float*)d_out;

    char* wsp = (char*)d_ws;
    float* ic  = (float*)(wsp);                // 512 KB
    float* u   = (float*)(wsp + 524288);       // 128 KB
    float* v   = (float*)(wsp + 655360);       // 128 KB
    float* sc  = (float*)(wsp + 786432);       // 512 KB
    float* ac  = (float*)(wsp + 1310720);      // 512 KB
    float* ssp = (float*)(wsp + 1835008);      // 128 KB [2][64][256]
    float* asp = (float*)(wsp + 1966080);      // 50 KB
    u16*   wsb2 = (u16*)(wsp + 2097152);       // 2 MB (repacked)

    k1_rowstats<<<dim3(32768), dim3(256), 0, stream>>>(img, ic);
    k2_hproj<<<dim3(512), dim3(256), 0, stream>>>(h, whc, bc, whs, bs, u, v);
    k2b_conv<<<dim3(512), dim3(256), 0, stream>>>(ws, wsb2);
    k3_sc<<<dim3(8, 64), dim3(256), 0, stream>>>(ic, u, wc, wci, bci, sc);
    k4_softmax_c<<<dim3(64), dim3(256), 0, stream>>>(sc, ac);
    k5_gemm<<<dim3(4, 2, 64), dim3(256), 0, stream>>>(img, wsb2, ac, v, wsi, ssp);
    k6_softmax_p<<<dim3(64), dim3(256), 0, stream>>>(ssp, bsi, asp);
    k7_out<<<dim3(25088), dim3(256), 0, stream>>>(img, ac, asp, out);
}